// Round 2
// baseline (188.084 us; speedup 1.0000x reference)
//
#include <hip/hip_runtime.h>
#include <hip/hip_fp16.h>

#define N_NODES 50000
#define N_EDGES 1600000
#define D 48

#define EPB 8192            // edges per prep block
#define PB  196             // ceil(N_EDGES/EPB)
#define NPB_D 50            // dst-bin size: 1000 bins exactly, balanced 4/CU grid
#define NBIN_D 1000

#define EMAX 2400           // per-dst-bin edge cap (mean 1600, sigma ~40 -> 20 sigma)
#define HS 52               // h/W LDS stride (16B-aligned, bank-spread; proven R10)

// ---------- workspace layout (bytes) ----------
#define RECD_OFF  0          // u32[PB*EPB] block-major: (src<<6)|dlocal
#define OFFLD_OFF 6422528    // u16[PB][NBIN_D+1]  (392,392 B)
#define ODEG_OFF  6815232    // i32[50000] global out-degree (atomic)
#define CI_OFF    7015424    // f32[50000]
#define SFEAT_OFF 7215616    // f16[50000*48] prescaled (optional)
#define SFEAT_END 12015616

// One kernel = count + scan + scatter for the dst-sort; src out-degrees go
// straight to a global atomic histogram (fire-and-forget, L2-side RMW).
// This removes the entire srcb/offls second pipeline (R1 theory).
__global__ __launch_bounds__(1024) void k_prep(const int* __restrict__ src,
                                               const int* __restrict__ dst,
                                               unsigned int* __restrict__ rec,
                                               unsigned short* __restrict__ offld,
                                               int* __restrict__ odeg) {
    __shared__ int cd[NBIN_D];                  // histogram, then cursor
    __shared__ int wsum[16], wexcl[16];
    __shared__ alignas(16) unsigned int bufd[EPB];
    int tid = threadIdx.x, p = blockIdx.x;
    int wave = tid >> 6, lane = tid & 63;
    int base = p * EPB;

    // int4 edge loads: N_EDGES%4==0 and EPB%4==0 -> quads never straddle the
    // valid tail, so per-quad masking is exact.
    int sv[8], dv[8];
    bool ok[8];
    const int4* s4p = (const int4*)src;
    const int4* d4p = (const int4*)dst;
    #pragma unroll
    for (int c = 0; c < 2; ++c) {
        int e4 = base + c * 4096 + tid * 4;
        bool v = (e4 < N_EDGES);
        int4 s4 = v ? s4p[e4 >> 2] : make_int4(0, 0, 0, 0);
        int4 d4 = v ? d4p[e4 >> 2] : make_int4(0, 0, 0, 0);
        sv[c * 4 + 0] = s4.x; sv[c * 4 + 1] = s4.y;
        sv[c * 4 + 2] = s4.z; sv[c * 4 + 3] = s4.w;
        dv[c * 4 + 0] = d4.x; dv[c * 4 + 1] = d4.y;
        dv[c * 4 + 2] = d4.z; dv[c * 4 + 3] = d4.w;
        ok[c * 4 + 0] = v; ok[c * 4 + 1] = v; ok[c * 4 + 2] = v; ok[c * 4 + 3] = v;
    }

    for (int i = tid; i < NBIN_D; i += 1024) cd[i] = 0;
    __syncthreads();
    #pragma unroll
    for (int k = 0; k < 8; ++k) {
        if (ok[k]) {
            atomicAdd(&cd[dv[k] / NPB_D], 1);
            atomicAdd(&odeg[sv[k]], 1);         // global, no return: latency-free
        }
    }
    __syncthreads();

    // wave-shuffle scan over cd (1000 elements, threads 0..999)
    int own = (tid < NBIN_D) ? cd[tid] : 0;
    int incl = own;
    #pragma unroll
    for (int o = 1; o < 64; o <<= 1) {
        int u = __shfl_up(incl, o);
        if (lane >= o) incl += u;
    }
    if (lane == 63) wsum[wave] = incl;
    __syncthreads();
    if (tid < 16) {
        int v = wsum[tid];
        int ic = v;
        #pragma unroll
        for (int o = 1; o < 16; o <<= 1) {
            int u = __shfl_up(ic, o);
            if (lane >= o) ic += u;
        }
        wexcl[tid] = ic - v;
    }
    __syncthreads();
    if (tid < NBIN_D) {
        int gincl = wexcl[wave] + incl;
        int ex = gincl - own;
        offld[p * (NBIN_D + 1) + tid] = (unsigned short)ex;
        cd[tid] = ex;                           // cursor
        if (tid == NBIN_D - 1) offld[p * (NBIN_D + 1) + NBIN_D] = (unsigned short)gincl;
    }
    __syncthreads();

    #pragma unroll
    for (int k = 0; k < 8; ++k) {
        if (ok[k]) {
            int s = sv[k], d = dv[k];
            int bin = d / NPB_D;
            int pd = atomicAdd(&cd[bin], 1);
            bufd[pd] = ((unsigned int)s << 6) | (unsigned int)(d - bin * NPB_D);
        }
    }
    __syncthreads();

    // coalesced full-line stream out
    int4* ro = (int4*)(rec + base);
    const int4* bi = (const int4*)bufd;
    for (int i = tid; i < EPB / 4; i += 1024) ro[i] = bi[i];
}

// Pure streaming: ci = rsqrt(max(odeg,1)); sfeat = feat * ci (fp16).
// One float4 unit (4 feats) per thread-iter; 12 units per node. 1172 blocks
// saturate the chip; no atomics, no scattered reads.
__global__ __launch_bounds__(512) void k_ci(const int* __restrict__ odeg,
                                            const float* __restrict__ feat,
                                            float* __restrict__ ci,
                                            __half* __restrict__ sfeat,
                                            int do_scale) {
    int i = blockIdx.x * 512 + threadIdx.x;     // float4-unit index
    if (i >= N_NODES * 12) return;
    int n = i / 12;
    float sc = rsqrtf(fmaxf((float)odeg[n], 1.0f));
    if (i - n * 12 == 0) ci[n] = sc;
    if (do_scale) {
        float4 f = ((const float4*)feat)[i];
        __half2 h0 = __float22half2_rn(make_float2(f.x * sc, f.y * sc));
        __half2 h1 = __float22half2_rn(make_float2(f.z * sc, f.w * sc));
        uint2 u;
        u.x = *(unsigned int*)&h0;
        u.y = *(unsigned int*)&h1;
        ((uint2*)sfeat)[i] = u;
    }
}

// Fused CSR-build + gather + GEMM: one block (8 waves, 512 thr) per 50-node bin.
// 1000 blocks, 4 blocks/CU -> all co-resident, balanced makespan.
template <bool PRESCALED>
__global__ __launch_bounds__(512, 8) void k_gcn(
    const unsigned int* __restrict__ rec, const unsigned short* __restrict__ offld,
    const float* __restrict__ ci, const __half* __restrict__ sfeat,
    const float* __restrict__ feat,
    const float* __restrict__ W, const float* __restrict__ b,
    float* __restrict__ out) {
    __shared__ int   colb[EMAX];        // 9.6 KB reordered local col (src ids)
    __shared__ float hl[NPB_D * HS];    // 10.4 KB
    __shared__ float Wl[D * HS];        // 10.0 KB
    __shared__ float bl[D];
    __shared__ int   ideg[NPB_D];
    __shared__ int   off[NPB_D];
    __shared__ int   cur[NPB_D];
    __shared__ int   runoff[PB + 1];
    __shared__ int   runpos[PB];
    __shared__ int   wsum[8], wexcl[8];
    int tid = threadIdx.x, bin = blockIdx.x;
    int wave = tid >> 6, lane = tid & 63;

    for (int i = tid; i < D * D; i += 512) Wl[(i / D) * HS + (i % D)] = W[i];
    if (tid < D) bl[tid] = b[tid];
    if (tid < NPB_D) { ideg[tid] = 0; cur[tid] = 0; }

    // ---- run table + wave-shuffle scan of run lengths ----
    int rlen = 0;
    if (tid < PB) {
        int o0 = offld[tid * (NBIN_D + 1) + bin];
        int o1 = offld[tid * (NBIN_D + 1) + bin + 1];
        rlen = o1 - o0;
        runpos[tid] = tid * EPB + o0;
    }
    int incl = rlen;
    #pragma unroll
    for (int o = 1; o < 64; o <<= 1) {
        int u = __shfl_up(incl, o);
        if (lane >= o) incl += u;
    }
    if (lane == 63) wsum[wave] = incl;
    __syncthreads();
    if (tid < 8) {
        int v = wsum[tid];
        int ic = v;
        #pragma unroll
        for (int o = 1; o < 8; o <<= 1) {
            int u = __shfl_up(ic, o);
            if (lane >= o) ic += u;
        }
        wexcl[tid] = ic - v;
        if (tid == 7) runoff[PB] = ic;
    }
    __syncthreads();
    if (tid < PB) runoff[tid] = wexcl[wave] + incl - rlen;
    __syncthreads();
    int cnt = runoff[PB];
    if (cnt > EMAX) cnt = EMAX;         // unreachable; guards LDS OOB

    // ---- Phase A: gather runs into regs (binary search), histogram, scan, reorder ----
    unsigned int rr[5];
    #pragma unroll
    for (int k = 0; k < 5; ++k) {
        int j = tid + k * 512;
        rr[k] = 0xFFFFFFFFu;
        if (j < cnt) {
            int lo = 0, hi = PB - 1;
            while (lo < hi) {
                int mid = (lo + hi + 1) >> 1;
                if (runoff[mid] <= j) lo = mid; else hi = mid - 1;
            }
            unsigned int r = rec[runpos[lo] + (j - runoff[lo])];
            rr[k] = r;
            atomicAdd(&ideg[r & 63], 1);
        }
    }
    __syncthreads();
    if (tid < NPB_D) {
        int v = ideg[tid];
        int ic = v;
        #pragma unroll
        for (int o = 1; o < 64; o <<= 1) {
            int u = __shfl_up(ic, o);
            if (tid >= o) ic += u;
        }
        off[tid] = ic - v;
    }
    __syncthreads();
    #pragma unroll
    for (int k = 0; k < 5; ++k) {
        if (rr[k] != 0xFFFFFFFFu) {
            int dl = rr[k] & 63;
            int p = atomicAdd(&cur[dl], 1);
            colb[off[dl] + p] = (int)(rr[k] >> 6);
        }
    }
    __syncthreads();

    // ---- Phase B: 16B-lane gather; node nl = q*8 + wave (wave-uniform bound) ----
    // 8 edge slots x 6 lanes (48 active): each lane loads 8 halves (uint4, 16B).
    int eslot = lane >> 3;              // 0..7
    int d8 = lane & 7;                  // 0..7; active when <6
    bool lane_ok = (d8 < 6);
    const float4* feat4 = (const float4*)feat;
    const uint4* sf = (const uint4*)sfeat;   // 16B = 8 halves per unit, 6/row

    for (int q = 0; q < 7; ++q) {
        int nl = q * 8 + wave;
        if (nl >= NPB_D) break;         // wave-uniform
        int n = bin * NPB_D + nl;
        int cb = off[nl];
        int deg = ideg[nl];

        float4 accA = make_float4(0.0f, 0.0f, 0.0f, 0.0f);
        float4 accB = make_float4(0.0f, 0.0f, 0.0f, 0.0f);
        for (int i0 = 0; i0 < deg; i0 += 8) {
            int ei = i0 + eslot;
            bool act = lane_ok && (ei < deg);
            int s = act ? colb[cb + ei] : 0;
            if (act) {
                if (PRESCALED) {
                    uint4 u = sf[(size_t)s * 6 + d8];
                    __half2 h0 = *reinterpret_cast<__half2*>(&u.x);
                    __half2 h1 = *reinterpret_cast<__half2*>(&u.y);
                    __half2 h2 = *reinterpret_cast<__half2*>(&u.z);
                    __half2 h3 = *reinterpret_cast<__half2*>(&u.w);
                    float2 f0 = __half22float2(h0);
                    float2 f1 = __half22float2(h1);
                    float2 f2 = __half22float2(h2);
                    float2 f3 = __half22float2(h3);
                    accA.x += f0.x; accA.y += f0.y; accA.z += f1.x; accA.w += f1.y;
                    accB.x += f2.x; accB.y += f2.y; accB.z += f3.x; accB.w += f3.y;
                } else {
                    float c = ci[s];    // 6 lanes same address: single line
                    float4 fa = feat4[(size_t)s * 12 + d8 * 2];
                    float4 fb = feat4[(size_t)s * 12 + d8 * 2 + 1];
                    accA.x = fmaf(fa.x, c, accA.x);
                    accA.y = fmaf(fa.y, c, accA.y);
                    accA.z = fmaf(fa.z, c, accA.z);
                    accA.w = fmaf(fa.w, c, accA.w);
                    accB.x = fmaf(fb.x, c, accB.x);
                    accB.y = fmaf(fb.y, c, accB.y);
                    accB.z = fmaf(fb.z, c, accB.z);
                    accB.w = fmaf(fb.w, c, accB.w);
                }
            }
        }
        // reduce 8 edge slots: xor-tree over lane bits 3..5 (slot index)
        #pragma unroll
        for (int m = 8; m <= 32; m <<= 1) {
            accA.x += __shfl_xor(accA.x, m);
            accA.y += __shfl_xor(accA.y, m);
            accA.z += __shfl_xor(accA.z, m);
            accA.w += __shfl_xor(accA.w, m);
            accB.x += __shfl_xor(accB.x, m);
            accB.y += __shfl_xor(accB.y, m);
            accB.z += __shfl_xor(accB.z, m);
            accB.w += __shfl_xor(accB.w, m);
        }
        if (lane < 6) {                 // slot 0, d8 = lane
            float4 rA, rB;
            if (deg > 0) {
                float cj = rsqrtf((float)deg);
                rA = make_float4(accA.x * cj, accA.y * cj, accA.z * cj, accA.w * cj);
                rB = make_float4(accB.x * cj, accB.y * cj, accB.z * cj, accB.w * cj);
            } else {
                rA = feat4[(size_t)n * 12 + lane * 2];
                rB = feat4[(size_t)n * 12 + lane * 2 + 1];
            }
            *(float4*)(hl + nl * HS + lane * 8) = rA;
            *(float4*)(hl + nl * HS + lane * 8 + 4) = rB;
        }
    }
    __syncthreads();

    // ---- Phase C: out = relu(h @ W^T + b), b128 LDS reads; 2 node-halves ----
    #pragma unroll
    for (int half = 0; half < 2; ++half) {
        int nl = (tid >> 4) + half * 32;
        int c = tid & 15;               // od = c, c+16, c+32
        if (nl < NPB_D) {
            int n = bin * NPB_D + nl;
            float a0 = bl[c], a1 = bl[c + 16], a2 = bl[c + 32];
            #pragma unroll
            for (int k4 = 0; k4 < 12; ++k4) {
                float4 hv = *(const float4*)(hl + nl * HS + k4 * 4);
                float4 w0 = *(const float4*)(Wl + c * HS + k4 * 4);
                float4 w1 = *(const float4*)(Wl + (c + 16) * HS + k4 * 4);
                float4 w2 = *(const float4*)(Wl + (c + 32) * HS + k4 * 4);
                a0 = fmaf(hv.x, w0.x, a0); a0 = fmaf(hv.y, w0.y, a0);
                a0 = fmaf(hv.z, w0.z, a0); a0 = fmaf(hv.w, w0.w, a0);
                a1 = fmaf(hv.x, w1.x, a1); a1 = fmaf(hv.y, w1.y, a1);
                a1 = fmaf(hv.z, w1.z, a1); a1 = fmaf(hv.w, w1.w, a1);
                a2 = fmaf(hv.x, w2.x, a2); a2 = fmaf(hv.y, w2.y, a2);
                a2 = fmaf(hv.z, w2.z, a2); a2 = fmaf(hv.w, w2.w, a2);
            }
            float* op = out + (size_t)n * D;
            op[c]      = fmaxf(a0, 0.0f);
            op[c + 16] = fmaxf(a1, 0.0f);
            op[c + 32] = fmaxf(a2, 0.0f);
        }
    }
}

extern "C" void kernel_launch(void* const* d_in, const int* in_sizes, int n_in,
                              void* d_out, int out_size, void* d_ws, size_t ws_size,
                              hipStream_t stream) {
    const float* feat = (const float*)d_in[0];
    const int*   src  = (const int*)d_in[1];
    const int*   dst  = (const int*)d_in[2];
    const float* W    = (const float*)d_in[3];
    const float* b    = (const float*)d_in[4];
    float* out = (float*)d_out;

    char* ws = (char*)d_ws;
    unsigned int*   rec   = (unsigned int*)(ws + RECD_OFF);
    unsigned short* offld = (unsigned short*)(ws + OFFLD_OFF);
    int*            odeg  = (int*)(ws + ODEG_OFF);
    float*          ci    = (float*)(ws + CI_OFF);
    __half*         sfeat = (__half*)(ws + SFEAT_OFF);

    const bool prescale = (ws_size >= (size_t)SFEAT_END);

    hipMemsetAsync(odeg, 0, (size_t)N_NODES * sizeof(int), stream);
    k_prep<<<PB, 1024, 0, stream>>>(src, dst, rec, offld, odeg);
    k_ci<<<(N_NODES * 12 + 511) / 512, 512, 0, stream>>>(odeg, feat, ci, sfeat,
                                                         prescale ? 1 : 0);
    if (prescale)
        k_gcn<true><<<NBIN_D, 512, 0, stream>>>(rec, offld, ci, sfeat, feat, W, b, out);
    else
        k_gcn<false><<<NBIN_D, 512, 0, stream>>>(rec, offld, ci, sfeat, feat, W, b, out);
}

// Round 3
// 137.772 us; speedup vs baseline: 1.3652x; 1.3652x over previous
//
#include <hip/hip_runtime.h>
#include <hip/hip_fp16.h>

#define N_NODES 50000
#define N_EDGES 1600000
#define D 48

#define EPB 8192            // edges per prep block
#define PB  196             // ceil(N_EDGES/EPB)
#define NPB_D 50            // dst-bin size: 1000 bins exactly, balanced 4/CU grid
#define NBIN_D 1000
#define NPB_S 256
#define NBIN_S 196          // ceil(50000/256)

#define EMAX 2400           // per-dst-bin edge cap (mean 1600, sigma ~40 -> 20 sigma)
#define HS 52               // h/W LDS stride (16B-aligned, bank-spread; proven R10)

// ---------- workspace layout (bytes) ----------
#define RECD_OFF  0          // u32[PB*EPB] block-major: (src<<6)|dlocal
#define SRCB_OFF  6422528    // u8 [PB*EPB] block-major: src&255
#define OFFLD_OFF 8028160    // u16[PB][NBIN_D+1]
#define OFFLS_OFF 8420552    // u16[PB][NBIN_S+1]
#define CI_OFF    8497776    // f32[50000]
#define SFEAT_OFF 8697776    // f16[50000*48] prescaled (optional)
#define SFEAT_END 13497776

// One kernel = count + scan + scatter, all block-local. Coalesced output only.
// (R2's global-atomic odeg variant measured 74us: 1.6M random global RMWs are
//  latency-bound. This LDS counting-sort pipeline is the proven-fast form.)
__global__ __launch_bounds__(1024) void k_prep(const int* __restrict__ src,
                                               const int* __restrict__ dst,
                                               unsigned int* __restrict__ rec,
                                               unsigned char* __restrict__ srcb,
                                               unsigned short* __restrict__ offld,
                                               unsigned short* __restrict__ offls) {
    __shared__ int cd[NBIN_D];                  // histogram, then cursor
    __shared__ int cs[NBIN_S];
    __shared__ int wsum[16], wexcl[16];
    __shared__ int wsum2[4], wexcl2[4];
    __shared__ alignas(16) unsigned int  bufd[EPB];
    __shared__ alignas(16) unsigned char bufs[EPB];
    int tid = threadIdx.x, p = blockIdx.x;
    int wave = tid >> 6, lane = tid & 63;
    int base = p * EPB;

    // int4 edge loads: N_EDGES%4==0 and EPB%4==0 -> quads never straddle the
    // valid tail, so per-quad masking is exact.
    int sv[8], dv[8];
    bool ok[8];
    const int4* s4p = (const int4*)src;
    const int4* d4p = (const int4*)dst;
    #pragma unroll
    for (int c = 0; c < 2; ++c) {
        int e4 = base + c * 4096 + tid * 4;
        bool v = (e4 < N_EDGES);
        int4 s4 = v ? s4p[e4 >> 2] : make_int4(0, 0, 0, 0);
        int4 d4 = v ? d4p[e4 >> 2] : make_int4(0, 0, 0, 0);
        sv[c * 4 + 0] = s4.x; sv[c * 4 + 1] = s4.y;
        sv[c * 4 + 2] = s4.z; sv[c * 4 + 3] = s4.w;
        dv[c * 4 + 0] = d4.x; dv[c * 4 + 1] = d4.y;
        dv[c * 4 + 2] = d4.z; dv[c * 4 + 3] = d4.w;
        ok[c * 4 + 0] = v; ok[c * 4 + 1] = v; ok[c * 4 + 2] = v; ok[c * 4 + 3] = v;
    }

    for (int i = tid; i < NBIN_D; i += 1024) cd[i] = 0;
    for (int i = tid; i < NBIN_S; i += 1024) cs[i] = 0;
    __syncthreads();
    #pragma unroll
    for (int k = 0; k < 8; ++k) {
        if (ok[k]) {
            atomicAdd(&cd[dv[k] / NPB_D], 1);
            atomicAdd(&cs[sv[k] >> 8], 1);
        }
    }
    __syncthreads();

    // wave-shuffle scan over cd (1000 elements, threads 0..999)
    int own = (tid < NBIN_D) ? cd[tid] : 0;
    int incl = own;
    #pragma unroll
    for (int o = 1; o < 64; o <<= 1) {
        int u = __shfl_up(incl, o);
        if (lane >= o) incl += u;
    }
    if (lane == 63) wsum[wave] = incl;
    __syncthreads();
    if (tid < 16) {
        int v = wsum[tid];
        int ic = v;
        #pragma unroll
        for (int o = 1; o < 16; o <<= 1) {
            int u = __shfl_up(ic, o);
            if (lane >= o) ic += u;
        }
        wexcl[tid] = ic - v;
    }
    __syncthreads();
    if (tid < NBIN_D) {
        int gincl = wexcl[wave] + incl;
        int ex = gincl - own;
        offld[p * (NBIN_D + 1) + tid] = (unsigned short)ex;
        cd[tid] = ex;                           // cursor
        if (tid == NBIN_D - 1) offld[p * (NBIN_D + 1) + NBIN_D] = (unsigned short)gincl;
    }

    // wave-shuffle scan over cs (196 elements, threads 0..195)
    int own2 = (tid < NBIN_S) ? cs[tid] : 0;
    int incl2 = own2;
    #pragma unroll
    for (int o = 1; o < 64; o <<= 1) {
        int u = __shfl_up(incl2, o);
        if (lane >= o) incl2 += u;
    }
    if (lane == 63 && wave < 4) wsum2[wave] = incl2;
    __syncthreads();
    if (tid < 4) {
        int v = wsum2[tid];
        int ic = v;
        #pragma unroll
        for (int o = 1; o < 4; o <<= 1) {
            int u = __shfl_up(ic, o);
            if (lane >= o) ic += u;
        }
        wexcl2[tid] = ic - v;
    }
    __syncthreads();
    if (tid < NBIN_S) {
        int gincl2 = wexcl2[wave] + incl2;
        int ex = gincl2 - own2;
        offls[p * (NBIN_S + 1) + tid] = (unsigned short)ex;
        cs[tid] = ex;                           // cursor
        if (tid == NBIN_S - 1) offls[p * (NBIN_S + 1) + NBIN_S] = (unsigned short)gincl2;
    }
    __syncthreads();

    #pragma unroll
    for (int k = 0; k < 8; ++k) {
        if (ok[k]) {
            int s = sv[k], d = dv[k];
            int bin = d / NPB_D;
            int pd = atomicAdd(&cd[bin], 1);
            bufd[pd] = ((unsigned int)s << 6) | (unsigned int)(d - bin * NPB_D);
            int ps = atomicAdd(&cs[s >> 8], 1);
            bufs[ps] = (unsigned char)s;
        }
    }
    __syncthreads();

    // coalesced full-line streams out
    int4* ro = (int4*)(rec + base);
    const int4* bi = (const int4*)bufd;
    for (int i = tid; i < EPB / 4; i += 1024) ro[i] = bi[i];
    unsigned int* so = (unsigned int*)(srcb + base);
    const unsigned int* bs = (const unsigned int*)bufs;
    for (int i = tid; i < EPB / 4; i += 1024) so[i] = bs[i];
}

// one block per src-bin: gather its PB runs, LDS histogram -> ci (+ fp16 sfeat)
__global__ __launch_bounds__(512) void k_ci(const unsigned char* __restrict__ srcb,
                                            const unsigned short* __restrict__ offls,
                                            const float* __restrict__ feat,
                                            float* __restrict__ ci,
                                            __half* __restrict__ sfeat,
                                            int do_scale) {
    __shared__ int cnt[NPB_S];
    __shared__ float cl[NPB_S];
    int tid = threadIdx.x, sb = blockIdx.x;
    for (int i = tid; i < NPB_S; i += 512) cnt[i] = 0;
    __syncthreads();
    int wave = tid >> 6, lane = tid & 63;
    for (int p = wave; p < PB; p += 8) {
        int beg = offls[p * (NBIN_S + 1) + sb];
        int end = offls[p * (NBIN_S + 1) + sb + 1];
        for (int j = beg + lane; j < end; j += 64)
            atomicAdd(&cnt[srcb[p * EPB + j]], 1);
    }
    __syncthreads();
    if (tid < NPB_S) {
        float c = rsqrtf(fmaxf((float)cnt[tid], 1.0f));
        cl[tid] = c;
        int n = sb * NPB_S + tid;
        if (n < N_NODES) ci[n] = c;
    }
    __syncthreads();
    if (do_scale) {
        int nb = sb * NPB_S;
        int lim2 = (min(NPB_S, N_NODES - nb)) * 24;   // half2 units (2 floats each)
        const float2* f2 = (const float2*)feat + (size_t)nb * 24;
        __half2* s2 = (__half2*)sfeat + (size_t)nb * 24;
        for (int i = tid; i < lim2; i += 512) {
            float sc = cl[i / 24];
            float2 f = f2[i];
            s2[i] = __float22half2_rn(make_float2(f.x * sc, f.y * sc));
        }
    }
}

// Fused CSR-build + gather + GEMM: one block (8 waves, 512 thr) per 50-node bin.
// 1000 blocks, 4 blocks/CU -> all co-resident, balanced makespan.
template <bool PRESCALED>
__global__ __launch_bounds__(512, 8) void k_gcn(
    const unsigned int* __restrict__ rec, const unsigned short* __restrict__ offld,
    const float* __restrict__ ci, const __half* __restrict__ sfeat,
    const float* __restrict__ feat,
    const float* __restrict__ W, const float* __restrict__ b,
    float* __restrict__ out) {
    __shared__ int   colb[EMAX];        // 9.6 KB reordered local col (src ids)
    __shared__ float hl[NPB_D * HS];    // 10.4 KB
    __shared__ float Wl[D * HS];        // 10.0 KB
    __shared__ float bl[D];
    __shared__ int   ideg[NPB_D];
    __shared__ int   off[NPB_D];
    __shared__ int   cur[NPB_D];
    __shared__ int   runoff[PB + 1];
    __shared__ int   runpos[PB];
    __shared__ int   wsum[8], wexcl[8];
    int tid = threadIdx.x, bin = blockIdx.x;
    int wave = tid >> 6, lane = tid & 63;

    for (int i = tid; i < D * D; i += 512) Wl[(i / D) * HS + (i % D)] = W[i];
    if (tid < D) bl[tid] = b[tid];
    if (tid < NPB_D) { ideg[tid] = 0; cur[tid] = 0; }

    // ---- run table + wave-shuffle scan of run lengths ----
    int rlen = 0;
    if (tid < PB) {
        int o0 = offld[tid * (NBIN_D + 1) + bin];
        int o1 = offld[tid * (NBIN_D + 1) + bin + 1];
        rlen = o1 - o0;
        runpos[tid] = tid * EPB + o0;
    }
    int incl = rlen;
    #pragma unroll
    for (int o = 1; o < 64; o <<= 1) {
        int u = __shfl_up(incl, o);
        if (lane >= o) incl += u;
    }
    if (lane == 63) wsum[wave] = incl;
    __syncthreads();
    if (tid < 8) {
        int v = wsum[tid];
        int ic = v;
        #pragma unroll
        for (int o = 1; o < 8; o <<= 1) {
            int u = __shfl_up(ic, o);
            if (lane >= o) ic += u;
        }
        wexcl[tid] = ic - v;
        if (tid == 7) runoff[PB] = ic;
    }
    __syncthreads();
    if (tid < PB) runoff[tid] = wexcl[wave] + incl - rlen;
    __syncthreads();
    int cnt = runoff[PB];
    if (cnt > EMAX) cnt = EMAX;         // unreachable; guards LDS OOB

    // ---- Phase A: gather runs into regs (binary search), histogram, scan, reorder ----
    unsigned int rr[5];
    #pragma unroll
    for (int k = 0; k < 5; ++k) {
        int j = tid + k * 512;
        rr[k] = 0xFFFFFFFFu;
        if (j < cnt) {
            int lo = 0, hi = PB - 1;
            while (lo < hi) {
                int mid = (lo + hi + 1) >> 1;
                if (runoff[mid] <= j) lo = mid; else hi = mid - 1;
            }
            unsigned int r = rec[runpos[lo] + (j - runoff[lo])];
            rr[k] = r;
            atomicAdd(&ideg[r & 63], 1);
        }
    }
    __syncthreads();
    if (tid < NPB_D) {
        int v = ideg[tid];
        int ic = v;
        #pragma unroll
        for (int o = 1; o < 64; o <<= 1) {
            int u = __shfl_up(ic, o);
            if (tid >= o) ic += u;
        }
        off[tid] = ic - v;
    }
    __syncthreads();
    #pragma unroll
    for (int k = 0; k < 5; ++k) {
        if (rr[k] != 0xFFFFFFFFu) {
            int dl = rr[k] & 63;
            int p = atomicAdd(&cur[dl], 1);
            colb[off[dl] + p] = (int)(rr[k] >> 6);
        }
    }
    __syncthreads();

    // ---- Phase B: 16B-lane gather, depth-2 software pipeline ----
    // 8 edge slots x 6 lanes (48 active). The naive loop serializes one L2/L3
    // round-trip per 8-edge chunk (guarded dynamic loop -> compiler waits
    // vmcnt(0) each iter). Here chunk i+1's colb read + gather are issued
    // BEFORE chunk i's convert/accumulate, so the wait is vmcnt(1) and the
    // memory latency overlaps the cvt/add work (R2 theory: latency-bound).
    int eslot = lane >> 3;              // 0..7
    int d8 = lane & 7;                  // 0..7; active when <6
    bool lane_ok = (d8 < 6);
    const float4* feat4 = (const float4*)feat;
    const uint4* sf = (const uint4*)sfeat;   // 16B = 8 halves per unit, 6/row

    for (int q = 0; q < 7; ++q) {
        int nl = q * 8 + wave;
        if (nl >= NPB_D) break;         // wave-uniform
        int n = bin * NPB_D + nl;
        int cb = off[nl];
        int deg = ideg[nl];

        float4 accA = make_float4(0.0f, 0.0f, 0.0f, 0.0f);
        float4 accB = make_float4(0.0f, 0.0f, 0.0f, 0.0f);

        if (PRESCALED) {
            bool acur = lane_ok && (eslot < deg);
            uint4 ucur = make_uint4(0, 0, 0, 0);
            if (acur) ucur = sf[(size_t)colb[cb + eslot] * 6 + d8];
            for (int i0 = 0; i0 < deg; i0 += 8) {
                int en = i0 + 8 + eslot;
                bool anxt = lane_ok && (en < deg);
                uint4 unxt = make_uint4(0, 0, 0, 0);
                if (anxt) unxt = sf[(size_t)colb[cb + en] * 6 + d8];
                if (acur) {
                    __half2 h0 = *reinterpret_cast<__half2*>(&ucur.x);
                    __half2 h1 = *reinterpret_cast<__half2*>(&ucur.y);
                    __half2 h2 = *reinterpret_cast<__half2*>(&ucur.z);
                    __half2 h3 = *reinterpret_cast<__half2*>(&ucur.w);
                    float2 f0 = __half22float2(h0);
                    float2 f1 = __half22float2(h1);
                    float2 f2 = __half22float2(h2);
                    float2 f3 = __half22float2(h3);
                    accA.x += f0.x; accA.y += f0.y; accA.z += f1.x; accA.w += f1.y;
                    accB.x += f2.x; accB.y += f2.y; accB.z += f3.x; accB.w += f3.y;
                }
                ucur = unxt;
                acur = anxt;
            }
        } else {
            bool acur = lane_ok && (eslot < deg);
            float ccur = 0.0f;
            float4 facur = make_float4(0.0f, 0.0f, 0.0f, 0.0f);
            float4 fbcur = make_float4(0.0f, 0.0f, 0.0f, 0.0f);
            if (acur) {
                int s = colb[cb + eslot];
                ccur = ci[s];
                facur = feat4[(size_t)s * 12 + d8 * 2];
                fbcur = feat4[(size_t)s * 12 + d8 * 2 + 1];
            }
            for (int i0 = 0; i0 < deg; i0 += 8) {
                int en = i0 + 8 + eslot;
                bool anxt = lane_ok && (en < deg);
                float cnxt = 0.0f;
                float4 fanxt = make_float4(0.0f, 0.0f, 0.0f, 0.0f);
                float4 fbnxt = make_float4(0.0f, 0.0f, 0.0f, 0.0f);
                if (anxt) {
                    int s = colb[cb + en];
                    cnxt = ci[s];
                    fanxt = feat4[(size_t)s * 12 + d8 * 2];
                    fbnxt = feat4[(size_t)s * 12 + d8 * 2 + 1];
                }
                if (acur) {
                    accA.x = fmaf(facur.x, ccur, accA.x);
                    accA.y = fmaf(facur.y, ccur, accA.y);
                    accA.z = fmaf(facur.z, ccur, accA.z);
                    accA.w = fmaf(facur.w, ccur, accA.w);
                    accB.x = fmaf(fbcur.x, ccur, accB.x);
                    accB.y = fmaf(fbcur.y, ccur, accB.y);
                    accB.z = fmaf(fbcur.z, ccur, accB.z);
                    accB.w = fmaf(fbcur.w, ccur, accB.w);
                }
                facur = fanxt; fbcur = fbnxt; ccur = cnxt; acur = anxt;
            }
        }

        // reduce 8 edge slots: xor-tree over lane bits 3..5 (slot index)
        #pragma unroll
        for (int m = 8; m <= 32; m <<= 1) {
            accA.x += __shfl_xor(accA.x, m);
            accA.y += __shfl_xor(accA.y, m);
            accA.z += __shfl_xor(accA.z, m);
            accA.w += __shfl_xor(accA.w, m);
            accB.x += __shfl_xor(accB.x, m);
            accB.y += __shfl_xor(accB.y, m);
            accB.z += __shfl_xor(accB.z, m);
            accB.w += __shfl_xor(accB.w, m);
        }
        if (lane < 6) {                 // slot 0, d8 = lane
            float4 rA, rB;
            if (deg > 0) {
                float cj = rsqrtf((float)deg);
                rA = make_float4(accA.x * cj, accA.y * cj, accA.z * cj, accA.w * cj);
                rB = make_float4(accB.x * cj, accB.y * cj, accB.z * cj, accB.w * cj);
            } else {
                rA = feat4[(size_t)n * 12 + lane * 2];
                rB = feat4[(size_t)n * 12 + lane * 2 + 1];
            }
            *(float4*)(hl + nl * HS + lane * 8) = rA;
            *(float4*)(hl + nl * HS + lane * 8 + 4) = rB;
        }
    }
    __syncthreads();

    // ---- Phase C: out = relu(h @ W^T + b), b128 LDS reads; 2 node-halves ----
    #pragma unroll
    for (int half = 0; half < 2; ++half) {
        int nl = (tid >> 4) + half * 32;
        int c = tid & 15;               // od = c, c+16, c+32
        if (nl < NPB_D) {
            int n = bin * NPB_D + nl;
            float a0 = bl[c], a1 = bl[c + 16], a2 = bl[c + 32];
            #pragma unroll
            for (int k4 = 0; k4 < 12; ++k4) {
                float4 hv = *(const float4*)(hl + nl * HS + k4 * 4);
                float4 w0 = *(const float4*)(Wl + c * HS + k4 * 4);
                float4 w1 = *(const float4*)(Wl + (c + 16) * HS + k4 * 4);
                float4 w2 = *(const float4*)(Wl + (c + 32) * HS + k4 * 4);
                a0 = fmaf(hv.x, w0.x, a0); a0 = fmaf(hv.y, w0.y, a0);
                a0 = fmaf(hv.z, w0.z, a0); a0 = fmaf(hv.w, w0.w, a0);
                a1 = fmaf(hv.x, w1.x, a1); a1 = fmaf(hv.y, w1.y, a1);
                a1 = fmaf(hv.z, w1.z, a1); a1 = fmaf(hv.w, w1.w, a1);
                a2 = fmaf(hv.x, w2.x, a2); a2 = fmaf(hv.y, w2.y, a2);
                a2 = fmaf(hv.z, w2.z, a2); a2 = fmaf(hv.w, w2.w, a2);
            }
            float* op = out + (size_t)n * D;
            op[c]      = fmaxf(a0, 0.0f);
            op[c + 16] = fmaxf(a1, 0.0f);
            op[c + 32] = fmaxf(a2, 0.0f);
        }
    }
}

extern "C" void kernel_launch(void* const* d_in, const int* in_sizes, int n_in,
                              void* d_out, int out_size, void* d_ws, size_t ws_size,
                              hipStream_t stream) {
    const float* feat = (const float*)d_in[0];
    const int*   src  = (const int*)d_in[1];
    const int*   dst  = (const int*)d_in[2];
    const float* W    = (const float*)d_in[3];
    const float* b    = (const float*)d_in[4];
    float* out = (float*)d_out;

    char* ws = (char*)d_ws;
    unsigned int*   rec   = (unsigned int*)(ws + RECD_OFF);
    unsigned char*  srcb  = (unsigned char*)(ws + SRCB_OFF);
    unsigned short* offld = (unsigned short*)(ws + OFFLD_OFF);
    unsigned short* offls = (unsigned short*)(ws + OFFLS_OFF);
    float*          ci    = (float*)(ws + CI_OFF);
    __half*         sfeat = (__half*)(ws + SFEAT_OFF);

    const bool prescale = (ws_size >= (size_t)SFEAT_END);

    k_prep<<<PB, 1024, 0, stream>>>(src, dst, rec, srcb, offld, offls);
    k_ci<<<NBIN_S, 512, 0, stream>>>(srcb, offls, feat, ci, sfeat, prescale ? 1 : 0);
    if (prescale)
        k_gcn<true><<<NBIN_D, 512, 0, stream>>>(rec, offld, ci, sfeat, feat, W, b, out);
    else
        k_gcn<false><<<NBIN_D, 512, 0, stream>>>(rec, offld, ci, sfeat, feat, W, b, out);
}

// Round 4
// 131.548 us; speedup vs baseline: 1.4298x; 1.0473x over previous
//
#include <hip/hip_runtime.h>
#include <hip/hip_fp16.h>

#define N_NODES 50000
#define N_EDGES 1600000
#define D 48

#define EPB 8192            // edges per prep block
#define PB  196             // ceil(N_EDGES/EPB)
#define NPB_D 50            // dst-bin size: 1000 bins exactly, balanced 4/CU grid
#define NBIN_D 1000

#define HB 128              // hist blocks; 1600000/128 = 12500 edges/slice exactly
#define ESL (N_EDGES / HB)  // 12500
#define HW ((N_NODES + 3) / 4)   // 12500 packed u32 words (4x u8 counters)

#define EMAX 2400           // per-dst-bin edge cap (mean 1600, sigma ~40 -> 20 sigma)
#define HS 52               // h/W LDS stride (16B-aligned, bank-spread; proven R10)

// ---------- workspace layout (bytes) ----------
#define RECD_OFF  0          // u32[PB*EPB] block-major: (src<<6)|dlocal
#define OFFLD_OFF 6422528    // u16[PB][NBIN_D+1]          -> end 6,814,920
#define CNT_OFF   6814920    // u32[HB][HW] packed byte counters -> end 13,214,920
#define CI_OFF    13214920   // f32[50000]                 -> end 13,414,920
#define SFEAT_OFF 13414928   // f16[50000*48], 16B-aligned -> end 18,214,928
#define SFEAT_END 18214928

// Out-degree histogram: 128 blocks, each histograms its 12500-edge slice into
// 50000 8-bit counters packed 4/u32 in 48.8 KB LDS (slice mean 0.25/node,
// max ~8 << 255), then flushes coalesced. Replaces the srcb/offls counting
// sort + byte-gather k_ci (R3 post-mortem: that path was ~15-20us of the 27us
// prep+ci budget, all latency/atomic-bound).
__global__ __launch_bounds__(512) void k_hist(const int* __restrict__ src,
                                              unsigned int* __restrict__ cnts) {
    __shared__ unsigned int hw[HW];     // 50 KB packed counters
    int tid = threadIdx.x, blk = blockIdx.x;
    for (int i = tid; i < HW; i += 512) hw[i] = 0;
    __syncthreads();
    const int4* s4 = (const int4*)(src + blk * ESL);   // ESL%4==0
    for (int i = tid; i < ESL / 4; i += 512) {
        int4 v = s4[i];
        atomicAdd(&hw[v.x >> 2], 1u << ((v.x & 3) * 8));
        atomicAdd(&hw[v.y >> 2], 1u << ((v.y & 3) * 8));
        atomicAdd(&hw[v.z >> 2], 1u << ((v.z & 3) * 8));
        atomicAdd(&hw[v.w >> 2], 1u << ((v.w & 3) * 8));
    }
    __syncthreads();
    unsigned int* o = cnts + (size_t)blk * HW;
    for (int i = tid; i < HW; i += 512) o[i] = hw[i];
}

// Merge 128 byte-counters per node (coalesced: 4 threads broadcast-share each
// u32 column) -> ci = rsqrt(max(deg,1)); fused fp16 prescale of the feature
// row (96 B contiguous per thread).
__global__ __launch_bounds__(512) void k_ci(const unsigned int* __restrict__ cnts,
                                            const float* __restrict__ feat,
                                            float* __restrict__ ci,
                                            __half* __restrict__ sfeat,
                                            int do_scale) {
    int n = blockIdx.x * 512 + threadIdx.x;
    if (n >= N_NODES) return;
    int w = n >> 2, sh = (n & 3) * 8;
    unsigned int s = 0;
    #pragma unroll 8
    for (int b = 0; b < HB; ++b) s += (cnts[(size_t)b * HW + w] >> sh) & 0xFFu;
    float c = rsqrtf(fmaxf((float)s, 1.0f));
    ci[n] = c;
    if (do_scale) {
        const float4* f4 = (const float4*)feat + (size_t)n * 12;
        uint2* o2 = (uint2*)sfeat + (size_t)n * 12;
        #pragma unroll
        for (int k = 0; k < 12; ++k) {
            float4 f = f4[k];
            __half2 h0 = __float22half2_rn(make_float2(f.x * c, f.y * c));
            __half2 h1 = __float22half2_rn(make_float2(f.z * c, f.w * c));
            o2[k] = make_uint2(*(unsigned int*)&h0, *(unsigned int*)&h1);
        }
    }
}

// Dst counting-sort only (src half removed: k_hist handles out-degrees).
// count + scan + scatter, all block-local; coalesced output.
__global__ __launch_bounds__(1024) void k_prep(const int* __restrict__ src,
                                               const int* __restrict__ dst,
                                               unsigned int* __restrict__ rec,
                                               unsigned short* __restrict__ offld) {
    __shared__ int cd[NBIN_D];                  // histogram, then cursor
    __shared__ int wsum[16], wexcl[16];
    __shared__ alignas(16) unsigned int bufd[EPB];
    int tid = threadIdx.x, p = blockIdx.x;
    int wave = tid >> 6, lane = tid & 63;
    int base = p * EPB;

    // int4 edge loads: N_EDGES%4==0 and EPB%4==0 -> quads never straddle the
    // valid tail, so per-quad masking is exact.
    int sv[8], dv[8];
    bool ok[8];
    const int4* s4p = (const int4*)src;
    const int4* d4p = (const int4*)dst;
    #pragma unroll
    for (int c = 0; c < 2; ++c) {
        int e4 = base + c * 4096 + tid * 4;
        bool v = (e4 < N_EDGES);
        int4 s4 = v ? s4p[e4 >> 2] : make_int4(0, 0, 0, 0);
        int4 d4 = v ? d4p[e4 >> 2] : make_int4(0, 0, 0, 0);
        sv[c * 4 + 0] = s4.x; sv[c * 4 + 1] = s4.y;
        sv[c * 4 + 2] = s4.z; sv[c * 4 + 3] = s4.w;
        dv[c * 4 + 0] = d4.x; dv[c * 4 + 1] = d4.y;
        dv[c * 4 + 2] = d4.z; dv[c * 4 + 3] = d4.w;
        ok[c * 4 + 0] = v; ok[c * 4 + 1] = v; ok[c * 4 + 2] = v; ok[c * 4 + 3] = v;
    }

    for (int i = tid; i < NBIN_D; i += 1024) cd[i] = 0;
    __syncthreads();
    #pragma unroll
    for (int k = 0; k < 8; ++k) {
        if (ok[k]) atomicAdd(&cd[dv[k] / NPB_D], 1);
    }
    __syncthreads();

    // wave-shuffle scan over cd (1000 elements, threads 0..999)
    int own = (tid < NBIN_D) ? cd[tid] : 0;
    int incl = own;
    #pragma unroll
    for (int o = 1; o < 64; o <<= 1) {
        int u = __shfl_up(incl, o);
        if (lane >= o) incl += u;
    }
    if (lane == 63) wsum[wave] = incl;
    __syncthreads();
    if (tid < 16) {
        int v = wsum[tid];
        int ic = v;
        #pragma unroll
        for (int o = 1; o < 16; o <<= 1) {
            int u = __shfl_up(ic, o);
            if (lane >= o) ic += u;
        }
        wexcl[tid] = ic - v;
    }
    __syncthreads();
    if (tid < NBIN_D) {
        int gincl = wexcl[wave] + incl;
        int ex = gincl - own;
        offld[p * (NBIN_D + 1) + tid] = (unsigned short)ex;
        cd[tid] = ex;                           // cursor
        if (tid == NBIN_D - 1) offld[p * (NBIN_D + 1) + NBIN_D] = (unsigned short)gincl;
    }
    __syncthreads();

    #pragma unroll
    for (int k = 0; k < 8; ++k) {
        if (ok[k]) {
            int s = sv[k], d = dv[k];
            int bin = d / NPB_D;
            int pd = atomicAdd(&cd[bin], 1);
            bufd[pd] = ((unsigned int)s << 6) | (unsigned int)(d - bin * NPB_D);
        }
    }
    __syncthreads();

    // coalesced full-line stream out
    int4* ro = (int4*)(rec + base);
    const int4* bi = (const int4*)bufd;
    for (int i = tid; i < EPB / 4; i += 1024) ro[i] = bi[i];
}

// Fused CSR-build + gather + GEMM: one block (8 waves, 512 thr) per 50-node bin.
// 1000 blocks, 4 blocks/CU -> all co-resident, balanced makespan.
template <bool PRESCALED>
__global__ __launch_bounds__(512, 8) void k_gcn(
    const unsigned int* __restrict__ rec, const unsigned short* __restrict__ offld,
    const float* __restrict__ ci, const __half* __restrict__ sfeat,
    const float* __restrict__ feat,
    const float* __restrict__ W, const float* __restrict__ b,
    float* __restrict__ out) {
    __shared__ int   colb[EMAX];        // 9.6 KB reordered local col (src ids)
    __shared__ float hl[NPB_D * HS];    // 10.4 KB
    __shared__ float Wl[D * HS];        // 10.0 KB
    __shared__ float bl[D];
    __shared__ int   ideg[NPB_D];
    __shared__ int   off[NPB_D];
    __shared__ int   cur[NPB_D];
    __shared__ int   runoff[PB + 1];
    __shared__ int   runpos[PB];
    __shared__ int   wsum[8], wexcl[8];
    int tid = threadIdx.x, bin = blockIdx.x;
    int wave = tid >> 6, lane = tid & 63;

    for (int i = tid; i < D * D; i += 512) Wl[(i / D) * HS + (i % D)] = W[i];
    if (tid < D) bl[tid] = b[tid];
    if (tid < NPB_D) { ideg[tid] = 0; cur[tid] = 0; }

    // ---- run table + wave-shuffle scan of run lengths ----
    int rlen = 0;
    if (tid < PB) {
        int o0 = offld[tid * (NBIN_D + 1) + bin];
        int o1 = offld[tid * (NBIN_D + 1) + bin + 1];
        rlen = o1 - o0;
        runpos[tid] = tid * EPB + o0;
    }
    int incl = rlen;
    #pragma unroll
    for (int o = 1; o < 64; o <<= 1) {
        int u = __shfl_up(incl, o);
        if (lane >= o) incl += u;
    }
    if (lane == 63) wsum[wave] = incl;
    __syncthreads();
    if (tid < 8) {
        int v = wsum[tid];
        int ic = v;
        #pragma unroll
        for (int o = 1; o < 8; o <<= 1) {
            int u = __shfl_up(ic, o);
            if (lane >= o) ic += u;
        }
        wexcl[tid] = ic - v;
        if (tid == 7) runoff[PB] = ic;
    }
    __syncthreads();
    if (tid < PB) runoff[tid] = wexcl[wave] + incl - rlen;
    __syncthreads();
    int cnt = runoff[PB];
    if (cnt > EMAX) cnt = EMAX;         // unreachable; guards LDS OOB

    // ---- Phase A: gather runs into regs (binary search), histogram, scan, reorder ----
    unsigned int rr[5];
    #pragma unroll
    for (int k = 0; k < 5; ++k) {
        int j = tid + k * 512;
        rr[k] = 0xFFFFFFFFu;
        if (j < cnt) {
            int lo = 0, hi = PB - 1;
            while (lo < hi) {
                int mid = (lo + hi + 1) >> 1;
                if (runoff[mid] <= j) lo = mid; else hi = mid - 1;
            }
            unsigned int r = rec[runpos[lo] + (j - runoff[lo])];
            rr[k] = r;
            atomicAdd(&ideg[r & 63], 1);
        }
    }
    __syncthreads();
    if (tid < NPB_D) {
        int v = ideg[tid];
        int ic = v;
        #pragma unroll
        for (int o = 1; o < 64; o <<= 1) {
            int u = __shfl_up(ic, o);
            if (tid >= o) ic += u;
        }
        off[tid] = ic - v;
    }
    __syncthreads();
    #pragma unroll
    for (int k = 0; k < 5; ++k) {
        if (rr[k] != 0xFFFFFFFFu) {
            int dl = rr[k] & 63;
            int p = atomicAdd(&cur[dl], 1);
            colb[off[dl] + p] = (int)(rr[k] >> 6);
        }
    }
    __syncthreads();

    // ---- Phase B: 16B-lane gather; node nl = q*8 + wave (wave-uniform bound) ----
    // 8 edge slots x 6 lanes (48 active): each lane loads 8 halves (uint4, 16B).
    // R0-R3 established this phase is line-transaction-bound (instr count,
    // width, and SW pipelining all neutral) -> keep the simple low-VGPR form.
    int eslot = lane >> 3;              // 0..7
    int d8 = lane & 7;                  // 0..7; active when <6
    bool lane_ok = (d8 < 6);
    const float4* feat4 = (const float4*)feat;
    const uint4* sf = (const uint4*)sfeat;   // 16B = 8 halves per unit, 6/row

    for (int q = 0; q < 7; ++q) {
        int nl = q * 8 + wave;
        if (nl >= NPB_D) break;         // wave-uniform
        int n = bin * NPB_D + nl;
        int cb = off[nl];
        int deg = ideg[nl];

        float4 accA = make_float4(0.0f, 0.0f, 0.0f, 0.0f);
        float4 accB = make_float4(0.0f, 0.0f, 0.0f, 0.0f);
        for (int i0 = 0; i0 < deg; i0 += 8) {
            int ei = i0 + eslot;
            bool act = lane_ok && (ei < deg);
            int s = act ? colb[cb + ei] : 0;
            if (act) {
                if (PRESCALED) {
                    uint4 u = sf[(size_t)s * 6 + d8];
                    __half2 h0 = *reinterpret_cast<__half2*>(&u.x);
                    __half2 h1 = *reinterpret_cast<__half2*>(&u.y);
                    __half2 h2 = *reinterpret_cast<__half2*>(&u.z);
                    __half2 h3 = *reinterpret_cast<__half2*>(&u.w);
                    float2 f0 = __half22float2(h0);
                    float2 f1 = __half22float2(h1);
                    float2 f2 = __half22float2(h2);
                    float2 f3 = __half22float2(h3);
                    accA.x += f0.x; accA.y += f0.y; accA.z += f1.x; accA.w += f1.y;
                    accB.x += f2.x; accB.y += f2.y; accB.z += f3.x; accB.w += f3.y;
                } else {
                    float c = ci[s];    // 6 lanes same address: single line
                    float4 fa = feat4[(size_t)s * 12 + d8 * 2];
                    float4 fb = feat4[(size_t)s * 12 + d8 * 2 + 1];
                    accA.x = fmaf(fa.x, c, accA.x);
                    accA.y = fmaf(fa.y, c, accA.y);
                    accA.z = fmaf(fa.z, c, accA.z);
                    accA.w = fmaf(fa.w, c, accA.w);
                    accB.x = fmaf(fb.x, c, accB.x);
                    accB.y = fmaf(fb.y, c, accB.y);
                    accB.z = fmaf(fb.z, c, accB.z);
                    accB.w = fmaf(fb.w, c, accB.w);
                }
            }
        }
        // reduce 8 edge slots: xor-tree over lane bits 3..5 (slot index)
        #pragma unroll
        for (int m = 8; m <= 32; m <<= 1) {
            accA.x += __shfl_xor(accA.x, m);
            accA.y += __shfl_xor(accA.y, m);
            accA.z += __shfl_xor(accA.z, m);
            accA.w += __shfl_xor(accA.w, m);
            accB.x += __shfl_xor(accB.x, m);
            accB.y += __shfl_xor(accB.y, m);
            accB.z += __shfl_xor(accB.z, m);
            accB.w += __shfl_xor(accB.w, m);
        }
        if (lane < 6) {                 // slot 0, d8 = lane
            float4 rA, rB;
            if (deg > 0) {
                float cj = rsqrtf((float)deg);
                rA = make_float4(accA.x * cj, accA.y * cj, accA.z * cj, accA.w * cj);
                rB = make_float4(accB.x * cj, accB.y * cj, accB.z * cj, accB.w * cj);
            } else {
                rA = feat4[(size_t)n * 12 + lane * 2];
                rB = feat4[(size_t)n * 12 + lane * 2 + 1];
            }
            *(float4*)(hl + nl * HS + lane * 8) = rA;
            *(float4*)(hl + nl * HS + lane * 8 + 4) = rB;
        }
    }
    __syncthreads();

    // ---- Phase C: out = relu(h @ W^T + b), b128 LDS reads; 2 node-halves ----
    #pragma unroll
    for (int half = 0; half < 2; ++half) {
        int nl = (tid >> 4) + half * 32;
        int c = tid & 15;               // od = c, c+16, c+32
        if (nl < NPB_D) {
            int n = bin * NPB_D + nl;
            float a0 = bl[c], a1 = bl[c + 16], a2 = bl[c + 32];
            #pragma unroll
            for (int k4 = 0; k4 < 12; ++k4) {
                float4 hv = *(const float4*)(hl + nl * HS + k4 * 4);
                float4 w0 = *(const float4*)(Wl + c * HS + k4 * 4);
                float4 w1 = *(const float4*)(Wl + (c + 16) * HS + k4 * 4);
                float4 w2 = *(const float4*)(Wl + (c + 32) * HS + k4 * 4);
                a0 = fmaf(hv.x, w0.x, a0); a0 = fmaf(hv.y, w0.y, a0);
                a0 = fmaf(hv.z, w0.z, a0); a0 = fmaf(hv.w, w0.w, a0);
                a1 = fmaf(hv.x, w1.x, a1); a1 = fmaf(hv.y, w1.y, a1);
                a1 = fmaf(hv.z, w1.z, a1); a1 = fmaf(hv.w, w1.w, a1);
                a2 = fmaf(hv.x, w2.x, a2); a2 = fmaf(hv.y, w2.y, a2);
                a2 = fmaf(hv.z, w2.z, a2); a2 = fmaf(hv.w, w2.w, a2);
            }
            float* op = out + (size_t)n * D;
            op[c]      = fmaxf(a0, 0.0f);
            op[c + 16] = fmaxf(a1, 0.0f);
            op[c + 32] = fmaxf(a2, 0.0f);
        }
    }
}

extern "C" void kernel_launch(void* const* d_in, const int* in_sizes, int n_in,
                              void* d_out, int out_size, void* d_ws, size_t ws_size,
                              hipStream_t stream) {
    const float* feat = (const float*)d_in[0];
    const int*   src  = (const int*)d_in[1];
    const int*   dst  = (const int*)d_in[2];
    const float* W    = (const float*)d_in[3];
    const float* b    = (const float*)d_in[4];
    float* out = (float*)d_out;

    char* ws = (char*)d_ws;
    unsigned int*   rec   = (unsigned int*)(ws + RECD_OFF);
    unsigned short* offld = (unsigned short*)(ws + OFFLD_OFF);
    unsigned int*   cnts  = (unsigned int*)(ws + CNT_OFF);
    float*          ci    = (float*)(ws + CI_OFF);
    __half*         sfeat = (__half*)(ws + SFEAT_OFF);

    const bool prescale = (ws_size >= (size_t)SFEAT_END);

    k_hist<<<HB, 512, 0, stream>>>(src, cnts);
    k_prep<<<PB, 1024, 0, stream>>>(src, dst, rec, offld);
    k_ci<<<(N_NODES + 511) / 512, 512, 0, stream>>>(cnts, feat, ci, sfeat,
                                                    prescale ? 1 : 0);
    if (prescale)
        k_gcn<true><<<NBIN_D, 512, 0, stream>>>(rec, offld, ci, sfeat, feat, W, b, out);
    else
        k_gcn<false><<<NBIN_D, 512, 0, stream>>>(rec, offld, ci, sfeat, feat, W, b, out);
}